// Round 1
// baseline (412.706 us; speedup 1.0000x reference)
//
#include <hip/hip_runtime.h>

#define IC 32
#define HDIM 64
#define WDIM 64
#define HW 4096
#define CHW (IC*HW)
#define NG 256
#define EPS 1e-5f

__device__ __forceinline__ float sigmoidf(float x){ return 1.0f/(1.0f+__expf(-x)); }
// swizzled float4-chunk slot for a 64x64 plane stored as 64 rows x 16 chunks
__device__ __forceinline__ int pslot(int r, int c4){ return (r<<4) + (c4 ^ ((r>>1)&7)); }
__device__ __forceinline__ float getc(const float4 v, int c){
  switch(c){ case 0: return v.x; case 1: return v.y; case 2: return v.z; default: return v.w; }
}

__global__ __launch_bounds__(256,1)
void ema_fused(const float* __restrict__ x,
               const float* __restrict__ sf_w, const float* __restrict__ sf_b,
               const float* __restrict__ lc_w, const float* __restrict__ lc_b,
               const float* __restrict__ gn_w, const float* __restrict__ gn_b,
               float* __restrict__ out)
{
  __shared__ __align__(16) float P[IC][128];   // row means [0..63], col means [64..127]
  __shared__ __align__(16) float HM[IC][64];
  __shared__ __align__(16) float WM[IC][64];
  __shared__ float4 plane[2][1024];            // double-buffered swizzled plane
  __shared__ float corn[IC][4];                // (0,0),(0,63),(63,0),(63,63)
  __shared__ float4 colscr[4][4][16];
  __shared__ float aw2s[IC], awgs[IC], Ts[IC], ga2v[IC];
  __shared__ float WcS[IC][9];
  __shared__ float stats[IC][2];
  __shared__ float sred[4];

  const int t = threadIdx.x;
  const int g = blockIdx.x;
  const float* __restrict__ xg = x + (size_t)g*CHW;
  float* __restrict__ og = out + (size_t)g*CHW;

  const int tx16 = t & 15, trow = t >> 4;   // pass1/stage mapping
  const int tx8  = t & 7,  tyg  = t >> 3;   // conv patch mapping (2 rows x 8 cols)

  if (t < IC){ stats[t][0]=0.f; stats[t][1]=0.f; }

  // ---------------- pass 1: row/col means, corners ----------------
  for (int iq = 0; iq < IC; iq += 4){
    float4 colp[4];
    #pragma unroll
    for (int ci = 0; ci < 4; ++ci){
      const int i = iq + ci;
      const float* cb = xg + i*HW + trow*WDIM + 4*tx16;
      float4 ca; ca.x=ca.y=ca.z=ca.w=0.f;
      #pragma unroll
      for (int k = 0; k < 4; ++k){
        const int r = k*16 + trow;
        float4 v = *(const float4*)(cb + k*1024);
        float rs = v.x+v.y+v.z+v.w;
        rs += __shfl_xor(rs, 1); rs += __shfl_xor(rs, 2);
        rs += __shfl_xor(rs, 4); rs += __shfl_xor(rs, 8);
        if (tx16 == 0) P[i][r] = rs * (1.0f/64.0f);
        ca.x+=v.x; ca.y+=v.y; ca.z+=v.z; ca.w+=v.w;
        if (r == 0){
          if (tx16==0)  corn[i][0]=v.x;
          if (tx16==15) corn[i][1]=v.w;
        } else if (r == 63){
          if (tx16==0)  corn[i][2]=v.x;
          if (tx16==15) corn[i][3]=v.w;
        }
      }
      colp[ci] = ca;
    }
    #pragma unroll
    for (int ci = 0; ci < 4; ++ci){
      float4 c = colp[ci];
      c.x += __shfl_xor(c.x,16); c.y += __shfl_xor(c.y,16);
      c.z += __shfl_xor(c.z,16); c.w += __shfl_xor(c.w,16);
      c.x += __shfl_xor(c.x,32); c.y += __shfl_xor(c.y,32);
      c.z += __shfl_xor(c.z,32); c.w += __shfl_xor(c.w,32);
      if ((t&63) < 16) colscr[ci][t>>6][tx16] = c;
    }
    __syncthreads();
    if (t < 64){
      const int ci = t>>4, tx = t&15;
      float4 a = colscr[ci][0][tx], b = colscr[ci][1][tx],
             c = colscr[ci][2][tx], d = colscr[ci][3][tx];
      float4 s;
      s.x=(a.x+b.x+c.x+d.x)*(1.f/64.f); s.y=(a.y+b.y+c.y+d.y)*(1.f/64.f);
      s.z=(a.z+b.z+c.z+d.z)*(1.f/64.f); s.w=(a.w+b.w+c.w+d.w)*(1.f/64.f);
      *(float4*)&P[iq+ci][64+4*tx] = s;
    }
    __syncthreads();
  }

  // ---------------- masks: fused 1x1 conv + sigmoid ----------------
  {
    const int l  = t & 127;
    const int ob = (t >> 7) << 4;   // 0 or 16
    float acc[16];
    #pragma unroll
    for (int q=0;q<16;q++) acc[q] = sf_b[ob+q];
    for (int i=0;i<IC;i++){
      const float p = P[i][l];
      #pragma unroll
      for (int q=0;q<16;q++) acc[q] = fmaf(sf_w[(ob+q)*IC+i], p, acc[q]);
    }
    #pragma unroll
    for (int q=0;q<16;q++){
      const float s = sigmoidf(acc[q]);
      if (l < 64) HM[ob+q][l] = s; else WM[ob+q][l-64] = s;
    }
  }

  // total sums per channel
  if (t < IC){
    float tt = 0.f;
    #pragma unroll
    for (int r4=0;r4<16;r4++){
      float4 v = *(const float4*)&P[t][4*r4];
      tt += v.x+v.y+v.z+v.w;
    }
    Ts[t] = tt * 64.0f;
  }
  __syncthreads();

  // ---------------- analytic mean(local) -> ga2 (8 lanes per o) ----------------
  {
    const int o = t >> 3, sl = t & 7;
    float dot = 0.f;
    #pragma unroll
    for (int ii=0; ii<4; ii++){
      const int i = sl + 8*ii;
      const float T   = Ts[i];
      const float r0  = 64.f*P[i][0],  r63 = 64.f*P[i][63];
      const float c0  = 64.f*P[i][64], c63 = 64.f*P[i][127];
      const float* w  = lc_w + (o*IC+i)*9;
      const float rex[3] = {r63, 0.f, r0};
      const float cex[3] = {c63, 0.f, c0};
      const float crn[3][3] = {{corn[i][3],0.f,corn[i][2]},
                               {0.f,0.f,0.f},
                               {corn[i][1],0.f,corn[i][0]}};
      #pragma unroll
      for (int ky=0;ky<3;ky++)
        #pragma unroll
        for (int kx=0;kx<3;kx++){
          const float S = T - rex[ky] - cex[kx] + crn[ky][kx];
          dot = fmaf(w[ky*3+kx], S, dot);
        }
    }
    dot += __shfl_xor(dot,1); dot += __shfl_xor(dot,2); dot += __shfl_xor(dot,4);
    if (sl == 0) ga2v[o] = lc_b[o] + dot*(1.0f/4096.0f);
  }
  __syncthreads();

  // ---------------- softmaxes: aw2 (per group), aw = softmax(gn_b), bconst ----------------
  if (t < IC){
    const int o = t;
    float a = ga2v[o];
    float m = a;
    m = fmaxf(m,__shfl_xor(m,1,32)); m = fmaxf(m,__shfl_xor(m,2,32));
    m = fmaxf(m,__shfl_xor(m,4,32)); m = fmaxf(m,__shfl_xor(m,8,32));
    m = fmaxf(m,__shfl_xor(m,16,32));
    float e = __expf(a-m);
    float s = e;
    s += __shfl_xor(s,1,32); s += __shfl_xor(s,2,32); s += __shfl_xor(s,4,32);
    s += __shfl_xor(s,8,32); s += __shfl_xor(s,16,32);
    aw2s[o] = e/s;

    float gb = gn_b[o];
    float m2 = gb;
    m2 = fmaxf(m2,__shfl_xor(m2,1,32)); m2 = fmaxf(m2,__shfl_xor(m2,2,32));
    m2 = fmaxf(m2,__shfl_xor(m2,4,32)); m2 = fmaxf(m2,__shfl_xor(m2,8,32));
    m2 = fmaxf(m2,__shfl_xor(m2,16,32));
    float e2 = __expf(gb-m2);
    float s2 = e2;
    s2 += __shfl_xor(s2,1,32); s2 += __shfl_xor(s2,2,32); s2 += __shfl_xor(s2,4,32);
    s2 += __shfl_xor(s2,8,32); s2 += __shfl_xor(s2,16,32);
    const float aw = e2/s2;
    awgs[o] = aw;
    float bc = aw * lc_b[o];
    bc += __shfl_xor(bc,1,32); bc += __shfl_xor(bc,2,32); bc += __shfl_xor(bc,4,32);
    bc += __shfl_xor(bc,8,32); bc += __shfl_xor(bc,16,32);
    if (o==0) sred[0] = bc;
  }
  __syncthreads();

  // collapsed conv filter Wc[i][k] = sum_o aw[o]*lc_w[o,i,k]
  for (int e = t; e < IC*9; e += 256){
    const int i = e/9, k = e - 9*i;
    float acc = 0.f;
    for (int o=0;o<IC;o++) acc = fmaf(awgs[o], lc_w[(o*IC+i)*9+k], acc);
    WcS[i][k] = acc;
  }
  __syncthreads();

  // ---------------- channel loop: stats + conv + alpha accumulation ----------------
  float acc[16];
  #pragma unroll
  for (int p=0;p<16;p++) acc[p]=0.f;
  float Kpart = 0.f;
  float4 cur[4], nxt[4];

  auto stage = [&](int i, const float4* v){
    float s1=0.f, s2=0.f;
    const float4 wm4 = *(const float4*)&WM[i][4*tx16];
    #pragma unroll
    for (int k=0;k<4;k++){
      const int r = k*16 + trow;
      const float hm = HM[i][r];
      const float mx = v[k].x*hm*wm4.x, my = v[k].y*hm*wm4.y,
                  mz = v[k].z*hm*wm4.z, mw = v[k].w*hm*wm4.w;
      s1 += mx+my+mz+mw;
      s2 += mx*mx+my*my+mz*mz+mw*mw;
      plane[i&1][pslot(r, tx16)] = v[k];
    }
    #pragma unroll
    for (int msk=1; msk<64; msk<<=1){
      s1 += __shfl_xor(s1, msk);
      s2 += __shfl_xor(s2, msk);
    }
    if ((t&63)==0){
      atomicAdd(&stats[i][0], s1);
      atomicAdd(&stats[i][1], s2);
    }
  };

  auto conv_alpha = [&](int i){
    const float s1 = stats[i][0], s2 = stats[i][1];
    const float mean = s1*(1.f/HW);
    const float var  = fmaxf(s2*(1.f/HW) - mean*mean, 0.f);
    const float rstd = rsqrtf(var + EPS);
    const float a2 = aw2s[i];
    const float gw = gn_w[i], gb = gn_b[i];
    const float ci = a2*gw*rstd;
    Kpart += a2*(gb - gw*rstd*mean);
    float wc[9];
    #pragma unroll
    for (int k9=0;k9<9;k9++) wc[k9] = WcS[i][k9];
    float4 c4[4][4];
    #pragma unroll
    for (int k=0;k<4;k++){
      const int r = 2*tyg - 1 + k;
      #pragma unroll
      for (int j=0;j<4;j++){
        const int cc = 2*tx8 - 1 + j;
        float4 vv;
        if (r>=0 && r<64 && cc>=0 && cc<16) vv = plane[i&1][pslot(r,cc)];
        else { vv.x=0.f; vv.y=0.f; vv.z=0.f; vv.w=0.f; }
        c4[k][j] = vv;
      }
    }
    const float hm0 = HM[i][2*tyg], hm1 = HM[i][2*tyg+1];
    const float4 wma = *(const float4*)&WM[i][8*tx8];
    const float4 wmb = *(const float4*)&WM[i][8*tx8+4];
    #pragma unroll
    for (int pr=0;pr<2;pr++){
      #pragma unroll
      for (int pc=0;pc<8;pc++){
        float s = 0.f;
        #pragma unroll
        for (int dr=0;dr<3;dr++){
          #pragma unroll
          for (int dc=0;dc<3;dc++){
            const int lc = pc + dc + 3;
            s = fmaf(getc(c4[pr+dr][lc>>2], lc&3), wc[dr*3+dc], s);
          }
        }
        const int lcc = pc + 4;
        const float ctr = getc(c4[pr+1][lcc>>2], lcc&3);
        const float wmv = (pc<4) ? getc(wma,pc) : getc(wmb,pc-4);
        acc[pr*8+pc] += s + ci*ctr*((pr==0)?hm0:hm1)*wmv;
      }
    }
  };

  {
    const float* cb0 = xg + trow*WDIM + 4*tx16;
    #pragma unroll
    for (int k=0;k<4;k++) cur[k] = *(const float4*)(cb0 + k*1024);
  }
  stage(0, cur);

  for (int i=0;i<IC;i++){
    __syncthreads();   // plane[i&1] + stats[i] ready; prior reads of plane[(i+1)&1] done
    if (i+1 < IC){
      const float* cbn = xg + (i+1)*HW + trow*WDIM + 4*tx16;
      #pragma unroll
      for (int k=0;k<4;k++) nxt[k] = *(const float4*)(cbn + k*1024);
    }
    conv_alpha(i);
    if (i+1 < IC) stage(i+1, nxt);
  }

  // ---------------- gate + write ----------------
  const float bconst = sred[0];
  float gate[16];
  #pragma unroll
  for (int p=0;p<16;p++) gate[p] = sigmoidf(acc[p] + bconst + Kpart);

  const int pbase = (2*tyg)*WDIM + 8*tx8;
  for (int i=0;i<IC;i++){
    const float* cb = xg + i*HW + pbase;
    float* ob = og + i*HW + pbase;
    #pragma unroll
    for (int pr=0;pr<2;pr++){
      float4 v0 = *(const float4*)(cb + pr*WDIM);
      float4 v1 = *(const float4*)(cb + pr*WDIM + 4);
      float4 o0, o1;
      o0.x = v0.x*gate[pr*8+0]; o0.y = v0.y*gate[pr*8+1];
      o0.z = v0.z*gate[pr*8+2]; o0.w = v0.w*gate[pr*8+3];
      o1.x = v1.x*gate[pr*8+4]; o1.y = v1.y*gate[pr*8+5];
      o1.z = v1.z*gate[pr*8+6]; o1.w = v1.w*gate[pr*8+7];
      *(float4*)(ob + pr*WDIM) = o0;
      *(float4*)(ob + pr*WDIM + 4) = o1;
    }
  }
}

extern "C" void kernel_launch(void* const* d_in, const int* in_sizes, int n_in,
                              void* d_out, int out_size, void* d_ws, size_t ws_size,
                              hipStream_t stream)
{
  (void)in_sizes; (void)n_in; (void)d_ws; (void)ws_size; (void)out_size;
  const float* x    = (const float*)d_in[0];
  const float* sfw  = (const float*)d_in[1];
  const float* sfb  = (const float*)d_in[2];
  const float* lcw  = (const float*)d_in[3];
  const float* lcb  = (const float*)d_in[4];
  const float* gnw  = (const float*)d_in[5];
  const float* gnb  = (const float*)d_in[6];
  ema_fused<<<NG, 256, 0, stream>>>(x, sfw, sfb, lcw, lcb, gnw, gnb, (float*)d_out);
}

// Round 2
// 381.496 us; speedup vs baseline: 1.0818x; 1.0818x over previous
//
#include <hip/hip_runtime.h>

#define IC 32
#define HW 4096
#define CHW (IC*HW)
#define NG 256
#define EPS 1e-5f
#define GCSZ 4432            // per-group consts: HM(2048) WM(2048) Wc(288 @4096) aw2(32 @4384) bconst(@4416)
#define WS_ROWCOL ((size_t)0)
#define WS_GC   ((size_t)NG*IC*132)
#define WS_PART (WS_GC + (size_t)NG*GCSZ)
#define WS_KP   (WS_PART + (size_t)NG*4*4096)

__device__ __forceinline__ float sigmoidf(float x){ return 1.0f/(1.0f+__expf(-x)); }
__device__ __forceinline__ int pslot(int r, int c4){ return (r<<4) + (c4 ^ ((r>>1)&7)); }
__device__ __forceinline__ float getc(const float4 v, int c){
  switch(c){ case 0: return v.x; case 1: return v.y; case 2: return v.z; default: return v.w; }
}

// ---------------- K1: per (group,channel) row/col sums + corners ----------------
__global__ __launch_bounds__(256)
void k1_rowcol(const float* __restrict__ x, float* __restrict__ ws)
{
  const int gid = blockIdx.x;                 // g*32 + i
  const float* __restrict__ p = x + (size_t)gid*HW;
  const int t = threadIdx.x;
  const int tx16 = t & 15, trow = t >> 4;

  __shared__ float rowS[64];
  __shared__ float4 colscr[4][16];
  __shared__ float corn4[4];

  float4 ca; ca.x=ca.y=ca.z=ca.w=0.f;
  #pragma unroll
  for (int k = 0; k < 4; ++k){
    const int r = k*16 + trow;
    float4 v = *(const float4*)(p + r*64 + 4*tx16);
    float rs = v.x+v.y+v.z+v.w;
    rs += __shfl_xor(rs,1); rs += __shfl_xor(rs,2);
    rs += __shfl_xor(rs,4); rs += __shfl_xor(rs,8);
    if (tx16 == 0) rowS[r] = rs;
    ca.x+=v.x; ca.y+=v.y; ca.z+=v.z; ca.w+=v.w;
    if (r == 0){
      if (tx16==0)  corn4[0]=v.x;
      if (tx16==15) corn4[1]=v.w;
    } else if (r == 63){
      if (tx16==0)  corn4[2]=v.x;
      if (tx16==15) corn4[3]=v.w;
    }
  }
  ca.x += __shfl_xor(ca.x,16); ca.y += __shfl_xor(ca.y,16);
  ca.z += __shfl_xor(ca.z,16); ca.w += __shfl_xor(ca.w,16);
  ca.x += __shfl_xor(ca.x,32); ca.y += __shfl_xor(ca.y,32);
  ca.z += __shfl_xor(ca.z,32); ca.w += __shfl_xor(ca.w,32);
  if ((t&63) < 16) colscr[t>>6][tx16] = ca;
  __syncthreads();

  float* base = ws + WS_ROWCOL + (size_t)gid*132;
  if (t < 64) base[t] = rowS[t];
  if (t < 16){
    float4 a = colscr[0][t], b = colscr[1][t], c = colscr[2][t], d = colscr[3][t];
    float4 s;
    s.x=a.x+b.x+c.x+d.x; s.y=a.y+b.y+c.y+d.y;
    s.z=a.z+b.z+c.z+d.z; s.w=a.w+b.w+c.w+d.w;
    *(float4*)(base + 64 + 4*t) = s;
  }
  if (t < 4) base[128+t] = corn4[t];
}

// ---------------- K2: per-group masks, aw2, Wc, bconst ----------------
__global__ __launch_bounds__(256)
void k2_masks(const float* __restrict__ sf_w, const float* __restrict__ sf_b,
              const float* __restrict__ lc_w, const float* __restrict__ lc_b,
              const float* __restrict__ gn_b, float* __restrict__ ws)
{
  __shared__ float P[IC][128];
  __shared__ float corn[IC][4];
  __shared__ float Ts[IC], ga2v[IC], awgs[IC];
  const int t = threadIdx.x;
  const int g = blockIdx.x;
  const float* __restrict__ rc = ws + WS_ROWCOL + (size_t)g*IC*132;
  float* __restrict__ gc = ws + WS_GC + (size_t)g*GCSZ;

  for (int idx=t; idx<IC*132; idx+=256){
    const int ch = idx/132, j = idx - 132*ch;
    const float v = rc[idx];
    if (j < 128) P[ch][j] = v*(1.f/64.f);
    else corn[ch][j-128] = v;
  }
  __syncthreads();

  // masks: fused 1x1 conv + sigmoid, written straight to ws
  {
    const int l  = t & 127;
    const int ob = (t >> 7) << 4;
    float acc[16];
    #pragma unroll
    for (int q=0;q<16;q++) acc[q] = sf_b[ob+q];
    for (int i=0;i<IC;i++){
      const float p = P[i][l];
      #pragma unroll
      for (int q=0;q<16;q++) acc[q] = fmaf(sf_w[(ob+q)*IC+i], p, acc[q]);
    }
    #pragma unroll
    for (int q=0;q<16;q++){
      const float s = sigmoidf(acc[q]);
      const int ch = ob+q;
      if (l < 64) gc[ch*64 + l] = s;
      else        gc[2048 + ch*64 + (l-64)] = s;
    }
  }
  if (t < IC){
    float tt = 0.f;
    #pragma unroll
    for (int r4=0;r4<16;r4++){
      float4 v = *(const float4*)&P[t][4*r4];
      tt += v.x+v.y+v.z+v.w;
    }
    Ts[t] = tt * 64.0f;
  }
  __syncthreads();

  // analytic mean(local) -> ga2 (8 lanes per o)
  {
    const int o = t >> 3, sl = t & 7;
    float dot = 0.f;
    #pragma unroll
    for (int ii=0; ii<4; ii++){
      const int i = sl + 8*ii;
      const float T   = Ts[i];
      const float r0  = 64.f*P[i][0],  r63 = 64.f*P[i][63];
      const float c0  = 64.f*P[i][64], c63 = 64.f*P[i][127];
      const float* w  = lc_w + (o*IC+i)*9;
      const float rex[3] = {r63, 0.f, r0};
      const float cex[3] = {c63, 0.f, c0};
      const float crn[3][3] = {{corn[i][3],0.f,corn[i][2]},
                               {0.f,0.f,0.f},
                               {corn[i][1],0.f,corn[i][0]}};
      #pragma unroll
      for (int ky=0;ky<3;ky++)
        #pragma unroll
        for (int kx=0;kx<3;kx++){
          const float S = T - rex[ky] - cex[kx] + crn[ky][kx];
          dot = fmaf(w[ky*3+kx], S, dot);
        }
    }
    dot += __shfl_xor(dot,1); dot += __shfl_xor(dot,2); dot += __shfl_xor(dot,4);
    if (sl == 0) ga2v[o] = lc_b[o] + dot*(1.0f/4096.0f);
  }
  __syncthreads();

  if (t < IC){
    const int o = t;
    float a = ga2v[o];
    float m = a;
    m = fmaxf(m,__shfl_xor(m,1,32)); m = fmaxf(m,__shfl_xor(m,2,32));
    m = fmaxf(m,__shfl_xor(m,4,32)); m = fmaxf(m,__shfl_xor(m,8,32));
    m = fmaxf(m,__shfl_xor(m,16,32));
    float e = __expf(a-m);
    float s = e;
    s += __shfl_xor(s,1,32); s += __shfl_xor(s,2,32); s += __shfl_xor(s,4,32);
    s += __shfl_xor(s,8,32); s += __shfl_xor(s,16,32);
    gc[4384 + o] = e/s;                       // aw2

    float gb = gn_b[o];
    float m2 = gb;
    m2 = fmaxf(m2,__shfl_xor(m2,1,32)); m2 = fmaxf(m2,__shfl_xor(m2,2,32));
    m2 = fmaxf(m2,__shfl_xor(m2,4,32)); m2 = fmaxf(m2,__shfl_xor(m2,8,32));
    m2 = fmaxf(m2,__shfl_xor(m2,16,32));
    float e2 = __expf(gb-m2);
    float s2 = e2;
    s2 += __shfl_xor(s2,1,32); s2 += __shfl_xor(s2,2,32); s2 += __shfl_xor(s2,4,32);
    s2 += __shfl_xor(s2,8,32); s2 += __shfl_xor(s2,16,32);
    const float aw = e2/s2;
    awgs[o] = aw;
    float bc = aw * lc_b[o];
    bc += __shfl_xor(bc,1,32); bc += __shfl_xor(bc,2,32); bc += __shfl_xor(bc,4,32);
    bc += __shfl_xor(bc,8,32); bc += __shfl_xor(bc,16,32);
    if (o==0) gc[4416] = bc;                  // bconst
  }
  __syncthreads();

  for (int e = t; e < IC*9; e += 256){
    const int i = e/9, k = e - 9*i;
    float acc = 0.f;
    for (int o=0;o<IC;o++) acc = fmaf(awgs[o], lc_w[(o*IC+i)*9+k], acc);
    gc[4096 + e] = acc;                       // Wc
  }
}

// ---------------- K3: per (group, 8-channel quarter): stats + conv + alpha ----------------
__global__ __launch_bounds__(256,4)
void k3_conv(const float* __restrict__ x, const float* __restrict__ gn_w,
             const float* __restrict__ gn_b, float* __restrict__ ws)
{
  const int blk = blockIdx.x;
  const int g = blk >> 2, q = blk & 3;
  const int ch0 = q*8;
  const float* __restrict__ xg = x + ((size_t)g*IC + ch0)*HW;
  const float* __restrict__ gc = ws + WS_GC + (size_t)g*GCSZ;

  __shared__ __align__(16) float HMs[8][64];
  __shared__ __align__(16) float WMs[8][64];
  __shared__ float4 plane[2][1024];
  __shared__ float WcL[72];
  __shared__ float aw2L[8], gnwL[8], gnbL[8];
  __shared__ float stats[8][2];

  const int t = threadIdx.x;
  const int tx16 = t & 15, trow = t >> 4;
  const int tx8  = t & 7,  tyg  = t >> 3;

  for (int idx=t; idx<512; idx+=256){
    const int ch = idx>>6, l = idx&63;
    HMs[ch][l] = gc[(ch0+ch)*64 + l];
    WMs[ch][l] = gc[2048 + (ch0+ch)*64 + l];
  }
  if (t < 72) WcL[t] = gc[4096 + ch0*9 + t];
  if (t < 8){
    aw2L[t] = gc[4384 + ch0 + t];
    gnwL[t] = gn_w[ch0 + t];
    gnbL[t] = gn_b[ch0 + t];
  }
  if (t < 16) stats[t>>1][t&1] = 0.f;
  __syncthreads();

  float acc[16];
  #pragma unroll
  for (int p=0;p<16;p++) acc[p]=0.f;
  float Kpart = 0.f;
  float4 cur[4], nxt[4];

  auto stage = [&](int i, const float4* v){
    float s1=0.f, s2=0.f;
    const float4 wm4 = *(const float4*)&WMs[i][4*tx16];
    #pragma unroll
    for (int k=0;k<4;k++){
      const int r = k*16 + trow;
      const float hm = HMs[i][r];
      const float mx = v[k].x*hm*wm4.x, my = v[k].y*hm*wm4.y,
                  mz = v[k].z*hm*wm4.z, mw = v[k].w*hm*wm4.w;
      s1 += mx+my+mz+mw;
      s2 += mx*mx+my*my+mz*mz+mw*mw;
      plane[i&1][pslot(r, tx16)] = v[k];
    }
    #pragma unroll
    for (int msk=1; msk<64; msk<<=1){
      s1 += __shfl_xor(s1, msk);
      s2 += __shfl_xor(s2, msk);
    }
    if ((t&63)==0){
      atomicAdd(&stats[i][0], s1);
      atomicAdd(&stats[i][1], s2);
    }
  };

  auto conv_alpha = [&](int i){
    const float s1 = stats[i][0], s2 = stats[i][1];
    const float mean = s1*(1.f/HW);
    const float var  = fmaxf(s2*(1.f/HW) - mean*mean, 0.f);
    const float rstd = rsqrtf(var + EPS);
    const float a2 = aw2L[i];
    const float gw = gnwL[i], gb = gnbL[i];
    const float ci = a2*gw*rstd;
    Kpart += a2*(gb - gw*rstd*mean);
    float wc[9];
    #pragma unroll
    for (int k9=0;k9<9;k9++) wc[k9] = WcL[i*9+k9];
    float4 c4[4][4];
    #pragma unroll
    for (int k=0;k<4;k++){
      const int r = 2*tyg - 1 + k;
      #pragma unroll
      for (int j=0;j<4;j++){
        const int cc = 2*tx8 - 1 + j;
        float4 vv;
        if (r>=0 && r<64 && cc>=0 && cc<16) vv = plane[i&1][pslot(r,cc)];
        else { vv.x=0.f; vv.y=0.f; vv.z=0.f; vv.w=0.f; }
        c4[k][j] = vv;
      }
    }
    const float hm0 = HMs[i][2*tyg], hm1 = HMs[i][2*tyg+1];
    const float4 wma = *(const float4*)&WMs[i][8*tx8];
    const float4 wmb = *(const float4*)&WMs[i][8*tx8+4];
    #pragma unroll
    for (int pr=0;pr<2;pr++){
      #pragma unroll
      for (int pc=0;pc<8;pc++){
        float s = 0.f;
        #pragma unroll
        for (int dr=0;dr<3;dr++){
          #pragma unroll
          for (int dc=0;dc<3;dc++){
            const int lc = pc + dc + 3;
            s = fmaf(getc(c4[pr+dr][lc>>2], lc&3), wc[dr*3+dc], s);
          }
        }
        const int lcc = pc + 4;
        const float ctr = getc(c4[pr+1][lcc>>2], lcc&3);
        const float wmv = (pc<4) ? getc(wma,pc) : getc(wmb,pc-4);
        acc[pr*8+pc] += s + ci*ctr*((pr==0)?hm0:hm1)*wmv;
      }
    }
  };

  {
    const float* cb0 = xg + trow*64 + 4*tx16;
    #pragma unroll
    for (int k=0;k<4;k++) cur[k] = *(const float4*)(cb0 + k*1024);
  }
  stage(0, cur);

  for (int i=0;i<8;i++){
    __syncthreads();
    if (i+1 < 8){
      const float* cbn = xg + (i+1)*HW + trow*64 + 4*tx16;
      #pragma unroll
      for (int k=0;k<4;k++) nxt[k] = *(const float4*)(cbn + k*1024);
    }
    conv_alpha(i);
    if (i+1 < 8) stage(i+1, nxt);
  }

  // write partial gate-logit plane + partial K
  float* pp = ws + WS_PART + (size_t)blk*4096;
  const int pbase = (2*tyg)*64 + 8*tx8;
  #pragma unroll
  for (int pr=0;pr<2;pr++){
    float4 o0, o1;
    o0.x=acc[pr*8+0]; o0.y=acc[pr*8+1]; o0.z=acc[pr*8+2]; o0.w=acc[pr*8+3];
    o1.x=acc[pr*8+4]; o1.y=acc[pr*8+5]; o1.z=acc[pr*8+6]; o1.w=acc[pr*8+7];
    *(float4*)(pp + pbase + pr*64)     = o0;
    *(float4*)(pp + pbase + pr*64 + 4) = o1;
  }
  if (t == 0) ws[WS_KP + blk] = Kpart;
}

// ---------------- K4: sum partials -> gate -> apply ----------------
__global__ __launch_bounds__(256,4)
void k4_apply(const float* __restrict__ x, const float* __restrict__ ws,
              float* __restrict__ out)
{
  const int blk = blockIdx.x;
  const int g = blk >> 2, band = blk & 3;
  const int t = threadIdx.x;
  const int row = t >> 4, c4 = t & 15;
  const int grow = band*16 + row;
  const int offs = grow*64 + 4*c4;

  const float* __restrict__ gc = ws + WS_GC + (size_t)g*GCSZ;

  float4 a; a.x=a.y=a.z=a.w=0.f;
  #pragma unroll
  for (int qq=0; qq<4; qq++){
    const float* pp = ws + WS_PART + ((size_t)(g*4+qq))*4096;
    float4 v = *(const float4*)(pp + offs);
    a.x+=v.x; a.y+=v.y; a.z+=v.z; a.w+=v.w;
  }
  float kp = gc[4416];
  #pragma unroll
  for (int qq=0; qq<4; qq++) kp += ws[WS_KP + g*4 + qq];

  float4 gate;
  gate.x = sigmoidf(a.x + kp); gate.y = sigmoidf(a.y + kp);
  gate.z = sigmoidf(a.z + kp); gate.w = sigmoidf(a.w + kp);

  const float* __restrict__ xg = x + (size_t)g*CHW;
  float* __restrict__ og = out + (size_t)g*CHW;
  #pragma unroll 4
  for (int i=0;i<IC;i++){
    float4 v = *(const float4*)(xg + i*HW + offs);
    float4 o;
    o.x = v.x*gate.x; o.y = v.y*gate.y; o.z = v.z*gate.z; o.w = v.w*gate.w;
    *(float4*)(og + i*HW + offs) = o;
  }
}

extern "C" void kernel_launch(void* const* d_in, const int* in_sizes, int n_in,
                              void* d_out, int out_size, void* d_ws, size_t ws_size,
                              hipStream_t stream)
{
  (void)in_sizes; (void)n_in; (void)ws_size; (void)out_size;
  const float* x    = (const float*)d_in[0];
  const float* sfw  = (const float*)d_in[1];
  const float* sfb  = (const float*)d_in[2];
  const float* lcw  = (const float*)d_in[3];
  const float* lcb  = (const float*)d_in[4];
  const float* gnw  = (const float*)d_in[5];
  const float* gnb  = (const float*)d_in[6];
  float* wsf = (float*)d_ws;
  float* out = (float*)d_out;

  k1_rowcol<<<NG*IC, 256, 0, stream>>>(x, wsf);
  k2_masks <<<NG,    256, 0, stream>>>(sfw, sfb, lcw, lcb, gnb, wsf);
  k3_conv  <<<NG*4,  256, 0, stream>>>(x, gnw, gnb, wsf);
  k4_apply <<<NG*4,  256, 0, stream>>>(x, wsf, out);
}